// Round 7
// baseline (25.208 us; speedup 1.0000x reference)
//
#include <hip/hip_runtime.h>
#include <hip/hip_bf16.h>

// x: [N=1024, C=3, T=300, V=25] float32 -> out: [N, T, V] float32
// angle = dot(h,d)/(|h||d|), h = x[:,16]-x[:,12], d = x[:,v]-x[:,16] (d=h at v=16)
// NaN->0, negative->+1. Joint-1 centering cancels algebraically.
//
// Round-6 structure with 4x fewer workgroups (dispatch-ramp experiment):
// block = 1024 threads covering 4096 consecutive floats (1 float4 group per
// thread, unchanged), grid = 1875. Param table: a 4096-float span touches
// <=165 joint-rows (+1 straddle) -> 166 rows staged by lanes 0..165
// (x16[3], h[3], 1/|h| each), one barrier, then ds_read_b128 fetches.
// Wave count (30K) and per-thread work identical to round 6.

#define CH_F 7500    // floats per channel per sample (T*V) == out floats per sample
#define N_F 22500    // floats per sample (3 channels)
#define LAST_ROW 307199  // N*T - 1
#define PROWS 166

typedef float f32x4 __attribute__((ext_vector_type(4)));

__global__ __launch_bounds__(1024) void symmetry_angle_ldsprm4k(
    const float* __restrict__ x, float* __restrict__ out) {
  __shared__ float prm[PROWS][8];   // x16_0,x16_1,x16_2,h0 | h1,h2,inv,pad

  const int B  = blockIdx.x * 4096;   // first flat float of this block
  const int R0 = B / 25;              // first global joint-row (n*300+t)
  const int lane = threadIdx.x;

  // ---- main-phase data loads issued first (independent of LDS) ----
  const int flat = B + (lane << 2);
  const int n = flat / CH_F;          // magic-mul
  const int r = flat - n * CH_F;      // multiple of 4; group never crosses n
  const float* xb = x + n * N_F;
  f32x4 a0 = *(const f32x4*)(xb + r);
  f32x4 a1 = *(const f32x4*)(xb + CH_F + r);
  f32x4 a2 = *(const f32x4*)(xb + 2 * CH_F + r);

  // ---- cooperative param staging: one row per lane (lanes 0..165) ----
  if (lane < PROWS) {
    int rt = R0 + lane;
    if (rt > LAST_ROW) rt = LAST_ROW;     // clamp (clamped slots never read)
    int nn = rt / 300;
    int base = rt * 25 + nn * 15000;      // = nn*22500 + t*25
    float x12_0 = x[base + 12];
    float x16_0 = x[base + 16];
    float x12_1 = x[base + CH_F + 12];
    float x16_1 = x[base + CH_F + 16];
    float x12_2 = x[base + 2 * CH_F + 12];
    float x16_2 = x[base + 2 * CH_F + 16];
    float h0 = x16_0 - x12_0;
    float h1 = x16_1 - x12_1;
    float h2 = x16_2 - x12_2;
    float inv = rsqrtf(h0 * h0 + h1 * h1 + h2 * h2);
    prm[lane][0] = x16_0; prm[lane][1] = x16_1;
    prm[lane][2] = x16_2; prm[lane][3] = h0;
    prm[lane][4] = h1;    prm[lane][5] = h2;
    prm[lane][6] = inv;   prm[lane][7] = 0.0f;
  }
  __syncthreads();

  // ---- fetch params for row of elem 0 and row+1 (unconditional) ----
  const int rt = flat / 25;           // global row of first element
  const int v0 = flat - rt * 25;      // 0..24
  const int lr = rt - R0;             // 0..164  (lr+1 <= 165 always staged)
  f32x4 pa0 = *(const f32x4*)&prm[lr][0];
  f32x4 pa1 = *(const f32x4*)&prm[lr][4];
  f32x4 pb0 = *(const f32x4*)&prm[lr + 1][0];
  f32x4 pb1 = *(const f32x4*)&prm[lr + 1][4];

  float e0[4] = {a0.x, a0.y, a0.z, a0.w};
  float e1[4] = {a1.x, a1.y, a1.z, a1.w};
  float e2[4] = {a2.x, a2.y, a2.z, a2.w};
  float res[4];
#pragma unroll
  for (int e = 0; e < 4; ++e) {
    int ve = v0 + e;
    bool second = ve >= 25;
    float X16 = second ? pb0.x : pa0.x;
    float Y16 = second ? pb0.y : pa0.y;
    float Z16 = second ? pb0.z : pa0.z;
    float H0  = second ? pb0.w : pa0.w;
    float H1  = second ? pb1.x : pa1.x;
    float H2  = second ? pb1.y : pa1.y;
    float INV = second ? pb1.z : pa1.z;
    int vv = second ? ve - 25 : ve;
    float d0, d1, d2;
    if (vv == 16) { d0 = H0; d1 = H1; d2 = H2; }
    else { d0 = e0[e] - X16; d1 = e1[e] - Y16; d2 = e2[e] - Z16; }
    float nd  = d0 * d0 + d1 * d1 + d2 * d2;
    float dot = H0 * d0 + H1 * d1 + H2 * d2;
    float ang = dot * INV * rsqrtf(nd);
    if (ang != ang) ang = 0.0f;      // nan_to_num
    if (ang < 0.0f) ang += 1.0f;     // where(angle<0, angle+1, angle)
    res[e] = ang;
  }
  f32x4 o = {res[0], res[1], res[2], res[3]};
  *(f32x4*)(out + flat) = o;
}

extern "C" void kernel_launch(void* const* d_in, const int* in_sizes, int n_in,
                              void* d_out, int out_size, void* d_ws, size_t ws_size,
                              hipStream_t stream) {
  const float* x = (const float*)d_in[0];
  float* out = (float*)d_out;
  // out_size = 7,680,000 floats -> 1875 blocks x 1024 threads x 4 floats
  int grid = out_size >> 12;
  symmetry_angle_ldsprm4k<<<grid, 1024, 0, stream>>>(x, out);
}

// Round 8
// 23.794 us; speedup vs baseline: 1.0594x; 1.0594x over previous
//
#include <hip/hip_runtime.h>
#include <hip/hip_bf16.h>

// x: [N=1024, C=3, T=300, V=25] float32 -> out: [N, T, V] float32
// angle = dot(h,d)/(|h||d|), h = x[:,16]-x[:,12], d = x[:,v]-x[:,16] (d=h at v=16)
// NaN->0, negative->+1. Joint-1 centering cancels algebraically.
//
// Round-6 structure (best: 24.0 us) + ONE change: non-temporal store for
// out (write-once stream) to avoid L2/L3 write-allocate evicting the input
// lines still needed by param staging / neighboring blocks.

#define CH_F 7500    // floats per channel per sample (T*V) == out floats per sample
#define N_F 22500    // floats per sample (3 channels)
#define LAST_ROW 307199  // N*T - 1

typedef float f32x4 __attribute__((ext_vector_type(4)));

__global__ __launch_bounds__(256) void symmetry_angle_ldsprm_nt(
    const float* __restrict__ x, float* __restrict__ out) {
  __shared__ float prm[43][8];   // x16_0,x16_1,x16_2,h0 | h1,h2,inv,pad

  const int B  = blockIdx.x * 1024;   // first flat float of this block
  const int R0 = B / 25;              // first global joint-row (n*300+t)
  const int lane = threadIdx.x;

  // ---- main-phase data loads issued first (independent of LDS) ----
  const int flat = B + (lane << 2);
  const int n = flat / CH_F;          // magic-mul
  const int r = flat - n * CH_F;      // multiple of 4; group never crosses n
  const float* xb = x + n * N_F;
  f32x4 a0 = *(const f32x4*)(xb + r);
  f32x4 a1 = *(const f32x4*)(xb + CH_F + r);
  f32x4 a2 = *(const f32x4*)(xb + 2 * CH_F + r);

  // ---- cooperative param staging: one row per lane (wave 0 only) ----
  if (lane < 43) {
    int rt = R0 + lane;
    if (rt > LAST_ROW) rt = LAST_ROW;     // clamp (clamped slots never read)
    int nn = rt / 300;
    int base = rt * 25 + nn * 15000;      // = nn*22500 + t*25
    float x12_0 = x[base + 12];
    float x16_0 = x[base + 16];
    float x12_1 = x[base + CH_F + 12];
    float x16_1 = x[base + CH_F + 16];
    float x12_2 = x[base + 2 * CH_F + 12];
    float x16_2 = x[base + 2 * CH_F + 16];
    float h0 = x16_0 - x12_0;
    float h1 = x16_1 - x12_1;
    float h2 = x16_2 - x12_2;
    float inv = rsqrtf(h0 * h0 + h1 * h1 + h2 * h2);
    prm[lane][0] = x16_0; prm[lane][1] = x16_1;
    prm[lane][2] = x16_2; prm[lane][3] = h0;
    prm[lane][4] = h1;    prm[lane][5] = h2;
    prm[lane][6] = inv;   prm[lane][7] = 0.0f;
  }
  __syncthreads();

  // ---- fetch params for row of elem 0 and row+1 (unconditional) ----
  const int rt = flat / 25;           // global row of first element
  const int v0 = flat - rt * 25;      // 0..24
  const int lr = rt - R0;             // 0..41  (lr+1 <= 42 always staged)
  f32x4 pa0 = *(const f32x4*)&prm[lr][0];
  f32x4 pa1 = *(const f32x4*)&prm[lr][4];
  f32x4 pb0 = *(const f32x4*)&prm[lr + 1][0];
  f32x4 pb1 = *(const f32x4*)&prm[lr + 1][4];

  float e0[4] = {a0.x, a0.y, a0.z, a0.w};
  float e1[4] = {a1.x, a1.y, a1.z, a1.w};
  float e2[4] = {a2.x, a2.y, a2.z, a2.w};
  float res[4];
#pragma unroll
  for (int e = 0; e < 4; ++e) {
    int ve = v0 + e;
    bool second = ve >= 25;
    float X16 = second ? pb0.x : pa0.x;
    float Y16 = second ? pb0.y : pa0.y;
    float Z16 = second ? pb0.z : pa0.z;
    float H0  = second ? pb0.w : pa0.w;
    float H1  = second ? pb1.x : pa1.x;
    float H2  = second ? pb1.y : pa1.y;
    float INV = second ? pb1.z : pa1.z;
    int vv = second ? ve - 25 : ve;
    float d0, d1, d2;
    if (vv == 16) { d0 = H0; d1 = H1; d2 = H2; }
    else { d0 = e0[e] - X16; d1 = e1[e] - Y16; d2 = e2[e] - Z16; }
    float nd  = d0 * d0 + d1 * d1 + d2 * d2;
    float dot = H0 * d0 + H1 * d1 + H2 * d2;
    float ang = dot * INV * rsqrtf(nd);
    if (ang != ang) ang = 0.0f;      // nan_to_num
    if (ang < 0.0f) ang += 1.0f;     // where(angle<0, angle+1, angle)
    res[e] = ang;
  }
  f32x4 o = {res[0], res[1], res[2], res[3]};
  __builtin_nontemporal_store(o, (f32x4*)(out + flat));
}

extern "C" void kernel_launch(void* const* d_in, const int* in_sizes, int n_in,
                              void* d_out, int out_size, void* d_ws, size_t ws_size,
                              hipStream_t stream) {
  const float* x = (const float*)d_in[0];
  float* out = (float*)d_out;
  // out_size = 7,680,000 floats -> 7500 blocks x 256 threads x 4 floats
  int grid = out_size >> 10;
  symmetry_angle_ldsprm_nt<<<grid, 256, 0, stream>>>(x, out);
}